// Round 1
// baseline (353.869 us; speedup 1.0000x reference)
//
#include <hip/hip_runtime.h>
#include <hip/hip_bf16.h>

#define BN 4
#define CC 256
#define C8 32
#define NN 4096
#define PROJ_ROWS 320

typedef __attribute__((ext_vector_type(8))) short short8;
typedef __attribute__((ext_vector_type(4))) float f32x4;

__device__ __forceinline__ unsigned short f2bf(float f) {
    unsigned u = __builtin_bit_cast(unsigned, f);
    unsigned r = (u + 0x7fffu + ((u >> 16) & 1u)) >> 16;
    return (unsigned short)r;
}

// ---------------------------------------------------------------------------
// Projection GEMM: for each batch, [320 x 256] @ [256 x 4096] + bias, bf16 out.
// Rows 0..31 (q) are written TRANSPOSED to qT[b][n][32] (A-operand-ready for
// the flash kernel); rows 32..63 (k) and 64..319 (v) go to proj[b][o][n].
// Grid: 4 b * 5 o-tiles * 16 n-tiles = 320 blocks, 256 threads.
// ---------------------------------------------------------------------------
__global__ __launch_bounds__(256) void proj_kernel(
    const float* __restrict__ x,
    const float* __restrict__ Wq, const float* __restrict__ bq,
    const float* __restrict__ Wk, const float* __restrict__ bk,
    const float* __restrict__ Wv, const float* __restrict__ bv,
    unsigned short* __restrict__ proj, unsigned short* __restrict__ qT)
{
    int bid = blockIdx.x;
    int nt   = bid & 15;
    int rest = bid >> 4;
    int ot   = rest % 5;
    int b    = rest / 5;
    int n0 = nt * 256;
    int o0 = ot * 64;
    int tid = threadIdx.x;
    int w = tid >> 6, l = tid & 63, l15 = l & 15, lq = l >> 4;

    // Wt: [64 o][256 c] bf16, stride 264 (528 B, 16B-aligned rows, 2-way banks)
    __shared__ alignas(16) unsigned short Wt[64][264];
    // Xt: [256 n][64 c] bf16 (transposed chunk), stride 88 (176 B)
    __shared__ alignas(16) unsigned short Xt[256][88];

    // stage full W tile (each pass: one o row, c = tid, coalesced)
    for (int o = 0; o < 64; o++) {
        int og = o0 + o;
        const float* src = (og < 32) ? (Wq + (size_t)og * CC)
                         : (og < 64) ? (Wk + (size_t)(og - 32) * CC)
                                     : (Wv + (size_t)(og - 64) * CC);
        Wt[o][tid] = f2bf(src[tid]);
    }

    f32x4 acc[16];
#pragma unroll
    for (int i = 0; i < 16; i++) acc[i] = (f32x4){0.f, 0.f, 0.f, 0.f};

    for (int kc = 0; kc < 4; kc++) {
        __syncthreads();
        // stage Xt: thread = one n (coalesced global reads along n), 8 c per b128
#pragma unroll
        for (int j = 0; j < 8; j++) {
            unsigned short tmp[8] __attribute__((aligned(16)));
#pragma unroll
            for (int i = 0; i < 8; i++) {
                tmp[i] = f2bf(x[(size_t)(b * CC + kc * 64 + j * 8 + i) * NN + n0 + tid]);
            }
            *(uint4*)&Xt[tid][j * 8] = *(const uint4*)tmp;
        }
        __syncthreads();
#pragma unroll
        for (int kh = 0; kh < 2; kh++) {
            short8 af = *(const short8*)&Wt[16 * w + l15][kc * 64 + kh * 32 + lq * 8];
#pragma unroll
            for (int ni = 0; ni < 16; ni++) {
                short8 bf = *(const short8*)&Xt[ni * 16 + l15][kh * 32 + lq * 8];
                acc[ni] = __builtin_amdgcn_mfma_f32_16x16x32_bf16(af, bf, acc[ni], 0, 0, 0);
            }
        }
    }

    // epilogue: bias + bf16 store. C/D layout: row = lq*4+r, col = l15.
#pragma unroll
    for (int r = 0; r < 4; r++) {
        int og = o0 + 16 * w + lq * 4 + r;
        float bias = (og < 32) ? bq[og] : (og < 64) ? bk[og - 32] : bv[og - 64];
#pragma unroll
        for (int ni = 0; ni < 16; ni++) {
            int n = n0 + ni * 16 + l15;
            unsigned short v16 = f2bf(acc[ni][r] + bias);
            if (og < 32) {
                qT[((size_t)b * NN + n) * C8 + og] = v16;      // q transposed
            } else {
                proj[((size_t)b * PROJ_ROWS + og) * NN + n] = v16;  // k, v
            }
        }
    }
}

// ---------------------------------------------------------------------------
// Flash attention over the QUERY axis (softmax normalizes over n per column m).
// Each block: one batch b, one 64-wide m-tile. 4 waves, 256 threads.
// Loop over n in steps of 64: S = Q_tile . K_m  (4 MFMA/wave),
// online softmax (per-column max/sum), P -> LDS (B-layout), O += V . P
// (32 MFMA/wave). Epilogue: out = gamma * O/Z + x.
// ---------------------------------------------------------------------------
__global__ __launch_bounds__(256) void attn_kernel(
    const unsigned short* __restrict__ proj,
    const unsigned short* __restrict__ qT,
    const float* __restrict__ x,
    const float* __restrict__ gamma_p,
    float* __restrict__ out)
{
    int bid = blockIdx.x;
    // XCD-aware swizzle: batch b -> XCD pair {2b, 2b+1} so per-batch v (2 MB)
    // stays resident in that XCD's 4 MB L2.
    int xcd = bid & 7;
    int b = xcd >> 1;
    int mtile = ((bid >> 3) << 1) | (xcd & 1);
    int m0 = mtile * 64;

    int tid = threadIdx.x;
    int w = tid >> 6, l = tid & 63, l15 = l & 15, lq = l >> 4;

    __shared__ alignas(16) unsigned short qs[64][40];   // [n][c8], stride 80 B
    __shared__ alignas(16) unsigned short vs[256][88];  // [c][n],  stride 176 B
    __shared__ alignas(16) unsigned short ps[64][88];   // [m][n],  stride 176 B
    __shared__ float red[2][4][64];                     // [max|sum][wave][m]

    const unsigned short* kbase = proj + ((size_t)b * PROJ_ROWS + C8) * NN;  // k rows
    const unsigned short* vbase = proj + ((size_t)b * PROJ_ROWS + 64) * NN;  // v rows
    const unsigned short* qbase = qT + (size_t)b * NN * C8;

    // K-side fragments (attention "queries" = k columns of this m-tile),
    // B-operand layout: lane holds k[c8 = lq*8+j][m = m0 + mi*16 + l15].
    short8 kfrag[4];
#pragma unroll
    for (int mi = 0; mi < 4; mi++) {
        int col = m0 + mi * 16 + l15;
        unsigned short t8[8] __attribute__((aligned(16)));
#pragma unroll
        for (int j = 0; j < 8; j++)
            t8[j] = kbase[(size_t)(lq * 8 + j) * NN + col];
        kfrag[mi] = *(const short8*)t8;
    }

    f32x4 O[4][4];
#pragma unroll
    for (int ci = 0; ci < 4; ci++)
#pragma unroll
        for (int mi = 0; mi < 4; mi++) O[ci][mi] = (f32x4){0.f, 0.f, 0.f, 0.f};

    float runM = -3e38f, runL = 0.f;  // lane tracks column m_local = l

    // register prefetch for iteration 0
    uint4 vreg[8];
    uint4 qreg;
#pragma unroll
    for (int i = 0; i < 8; i++) {
        int chunk = i * 256 + tid;
        int c = chunk >> 3, ch = chunk & 7;
        vreg[i] = *(const uint4*)(vbase + (size_t)c * NN + ch * 8);
    }
    {
        int n = tid >> 2, part = tid & 3;
        qreg = *(const uint4*)(qbase + (size_t)n * C8 + part * 8);
    }

    for (int it = 0; it < 64; it++) {
        __syncthreads();  // previous PV done reading vs/ps
        // commit staged tiles to LDS
#pragma unroll
        for (int i = 0; i < 8; i++) {
            int chunk = i * 256 + tid;
            int c = chunk >> 3, ch = chunk & 7;
            *(uint4*)&vs[c][ch * 8] = vreg[i];
        }
        {
            int n = tid >> 2, part = tid & 3;
            *(uint4*)&qs[n][part * 8] = qreg;
        }
        __syncthreads();

        // S = q-rows x k-cols : wave w owns n rows [16w, 16w+16)
        short8 af = *(const short8*)&qs[16 * w + l15][lq * 8];
        f32x4 S[4];
#pragma unroll
        for (int mi = 0; mi < 4; mi++)
            S[mi] = __builtin_amdgcn_mfma_f32_16x16x32_bf16(
                af, kfrag[mi], (f32x4){0.f, 0.f, 0.f, 0.f}, 0, 0, 0);

        // per-column (over n) band max within this wave's 16 rows
#pragma unroll
        for (int mi = 0; mi < 4; mi++) {
            float m_ = fmaxf(fmaxf(S[mi][0], S[mi][1]), fmaxf(S[mi][2], S[mi][3]));
            m_ = fmaxf(m_, __shfl_xor(m_, 16));
            m_ = fmaxf(m_, __shfl_xor(m_, 32));
            red[0][w][mi * 16 + l15] = m_;  // duplicate same-value writes: benign
        }
        __syncthreads();

        // running max update (each wave redundantly; lane owns column m = l)
        float tm = fmaxf(fmaxf(red[0][0][l], red[0][1][l]),
                         fmaxf(red[0][2][l], red[0][3][l]));
        float Mnew = fmaxf(runM, tm);
        float alpha = __expf(runM - Mnew);
        runM = Mnew;
        float Mn[4], Al[4];
#pragma unroll
        for (int mi = 0; mi < 4; mi++) {
            int src = mi * 16 + l15;
            Mn[mi] = __shfl(Mnew, src);
            Al[mi] = __shfl(alpha, src);
        }
        // rescale accumulators (alpha depends only on column)
#pragma unroll
        for (int ci = 0; ci < 4; ci++)
#pragma unroll
            for (int mi = 0; mi < 4; mi++) O[ci][mi] *= Al[mi];

        // P = exp(S - Mnew), write to ps[m][n] (B-operand-ready), column sums
#pragma unroll
        for (int mi = 0; mi < 4; mi++) {
            float s = 0.f;
            unsigned short pb[4];
#pragma unroll
            for (int r = 0; r < 4; r++) {
                float p = __expf(S[mi][r] - Mn[mi]);
                s += p;
                pb[r] = f2bf(p);
            }
            unsigned pk0 = (unsigned)pb[0] | ((unsigned)pb[1] << 16);
            unsigned pk1 = (unsigned)pb[2] | ((unsigned)pb[3] << 16);
            *(uint2*)&ps[mi * 16 + l15][16 * w + lq * 4] = make_uint2(pk0, pk1);
            s += __shfl_xor(s, 16);
            s += __shfl_xor(s, 32);
            red[1][w][mi * 16 + l15] = s;
        }
        __syncthreads();

        float ts = red[1][0][l] + red[1][1][l] + red[1][2][l] + red[1][3][l];
        runL = runL * alpha + ts;

        // prefetch next n-tile into registers (overlaps with PV MFMAs)
        if (it < 63) {
            int n0 = (it + 1) * 64;
#pragma unroll
            for (int i = 0; i < 8; i++) {
                int chunk = i * 256 + tid;
                int c = chunk >> 3, ch = chunk & 7;
                vreg[i] = *(const uint4*)(vbase + (size_t)c * NN + n0 + ch * 8);
            }
            int n = tid >> 2, part = tid & 3;
            qreg = *(const uint4*)(qbase + (size_t)(n0 + n) * C8 + part * 8);
        }

        // O[c,m] += V[c,n] . P[n,m] ; wave w owns c rows [64w, 64w+64)
#pragma unroll
        for (int kh = 0; kh < 2; kh++) {
            short8 bfr[4];
#pragma unroll
            for (int mi = 0; mi < 4; mi++)
                bfr[mi] = *(const short8*)&ps[mi * 16 + l15][kh * 32 + lq * 8];
#pragma unroll
            for (int ci = 0; ci < 4; ci++) {
                short8 av = *(const short8*)&vs[64 * w + ci * 16 + l15][kh * 32 + lq * 8];
#pragma unroll
                for (int mi = 0; mi < 4; mi++)
                    O[ci][mi] = __builtin_amdgcn_mfma_f32_16x16x32_bf16(
                        av, bfr[mi], O[ci][mi], 0, 0, 0);
            }
        }
    }

    // epilogue: out = gamma * O/Z + x
    float invl = 1.0f / runL;
    float iv[4];
#pragma unroll
    for (int mi = 0; mi < 4; mi++) iv[mi] = __shfl(invl, mi * 16 + l15);
    float gamma = gamma_p[0];
#pragma unroll
    for (int ci = 0; ci < 4; ci++) {
#pragma unroll
        for (int mi = 0; mi < 4; mi++) {
            int m = m0 + mi * 16 + l15;
#pragma unroll
            for (int r = 0; r < 4; r++) {
                int c = 64 * w + ci * 16 + lq * 4 + r;
                size_t idx = ((size_t)b * CC + c) * NN + m;
                out[idx] = gamma * (O[ci][mi][r] * iv[mi]) + x[idx];
            }
        }
    }
}

extern "C" void kernel_launch(void* const* d_in, const int* in_sizes, int n_in,
                              void* d_out, int out_size, void* d_ws, size_t ws_size,
                              hipStream_t stream) {
    const float* x     = (const float*)d_in[0];
    const float* Wq    = (const float*)d_in[1];
    const float* bq    = (const float*)d_in[2];
    const float* Wk    = (const float*)d_in[3];
    const float* bk    = (const float*)d_in[4];
    const float* Wv    = (const float*)d_in[5];
    const float* bv    = (const float*)d_in[6];
    const float* gamma = (const float*)d_in[7];
    float* out = (float*)d_out;

    // workspace layout (bf16): proj [4][320][4096] then qT [4][4096][32]
    unsigned short* proj = (unsigned short*)d_ws;
    unsigned short* qT   = proj + (size_t)BN * PROJ_ROWS * NN;
    (void)in_sizes; (void)n_in; (void)out_size; (void)ws_size;

    proj_kernel<<<320, 256, 0, stream>>>(x, Wq, bq, Wk, bk, Wv, bv, proj, qT);
    attn_kernel<<<256, 256, 0, stream>>>(proj, qT, x, gamma, out);
}

// Round 2
// 334.502 us; speedup vs baseline: 1.0579x; 1.0579x over previous
//
#include <hip/hip_runtime.h>
#include <hip/hip_bf16.h>

#define BN 4
#define CC 256
#define C8 32
#define NN 4096
#define PROJ_ROWS 320

typedef __attribute__((ext_vector_type(8))) short short8;
typedef __attribute__((ext_vector_type(4))) float f32x4;

__device__ __forceinline__ unsigned short f2bf(float f) {
    unsigned u = __builtin_bit_cast(unsigned, f);
    unsigned r = (u + 0x7fffu + ((u >> 16) & 1u)) >> 16;
    return (unsigned short)r;
}

// ---------------------------------------------------------------------------
// Projection GEMM (unchanged from R1, known-correct): per batch
// [320 x 256] @ [256 x 4096] + bias -> bf16. q rows transposed to qT[b][n][32].
// ---------------------------------------------------------------------------
__global__ __launch_bounds__(256) void proj_kernel(
    const float* __restrict__ x,
    const float* __restrict__ Wq, const float* __restrict__ bq,
    const float* __restrict__ Wk, const float* __restrict__ bk,
    const float* __restrict__ Wv, const float* __restrict__ bv,
    unsigned short* __restrict__ proj, unsigned short* __restrict__ qT)
{
    int bid = blockIdx.x;
    int nt   = bid & 15;
    int rest = bid >> 4;
    int ot   = rest % 5;
    int b    = rest / 5;
    int n0 = nt * 256;
    int o0 = ot * 64;
    int tid = threadIdx.x;
    int w = tid >> 6, l = tid & 63, l15 = l & 15, lq = l >> 4;

    __shared__ alignas(16) unsigned short Wt[64][264];
    __shared__ alignas(16) unsigned short Xt[256][88];

    for (int o = 0; o < 64; o++) {
        int og = o0 + o;
        const float* src = (og < 32) ? (Wq + (size_t)og * CC)
                         : (og < 64) ? (Wk + (size_t)(og - 32) * CC)
                                     : (Wv + (size_t)(og - 64) * CC);
        Wt[o][tid] = f2bf(src[tid]);
    }

    f32x4 acc[16];
#pragma unroll
    for (int i = 0; i < 16; i++) acc[i] = (f32x4){0.f, 0.f, 0.f, 0.f};

    for (int kc = 0; kc < 4; kc++) {
        __syncthreads();
#pragma unroll
        for (int j = 0; j < 8; j++) {
            unsigned short tmp[8] __attribute__((aligned(16)));
#pragma unroll
            for (int i = 0; i < 8; i++) {
                tmp[i] = f2bf(x[(size_t)(b * CC + kc * 64 + j * 8 + i) * NN + n0 + tid]);
            }
            *(uint4*)&Xt[tid][j * 8] = *(const uint4*)tmp;
        }
        __syncthreads();
#pragma unroll
        for (int kh = 0; kh < 2; kh++) {
            short8 af = *(const short8*)&Wt[16 * w + l15][kc * 64 + kh * 32 + lq * 8];
#pragma unroll
            for (int ni = 0; ni < 16; ni++) {
                short8 bf = *(const short8*)&Xt[ni * 16 + l15][kh * 32 + lq * 8];
                acc[ni] = __builtin_amdgcn_mfma_f32_16x16x32_bf16(af, bf, acc[ni], 0, 0, 0);
            }
        }
    }

#pragma unroll
    for (int r = 0; r < 4; r++) {
        int og = o0 + 16 * w + lq * 4 + r;
        float bias = (og < 32) ? bq[og] : (og < 64) ? bk[og - 32] : bv[og - 64];
#pragma unroll
        for (int ni = 0; ni < 16; ni++) {
            int n = n0 + ni * 16 + l15;
            unsigned short v16 = f2bf(acc[ni][r] + bias);
            if (og < 32) {
                qT[((size_t)b * NN + n) * C8 + og] = v16;
            } else {
                proj[((size_t)b * PROJ_ROWS + og) * NN + n] = v16;
            }
        }
    }
}

// ---------------------------------------------------------------------------
// Flash attention over the query axis, NO max subtraction (energy |S| < ~30,
// exp(S) safe in fp32; softmax is shift-invariant so result identical).
// n-range split across NSPLIT blocks; partials O_h, L_h combine linearly.
// 2 barriers/iteration; S for iter i+1 computed during iter i's PV phase;
// q fragments loaded straight from global (A-operand-ready qT layout).
// LDS strides = 72 shorts (144 B = 128+16 -> 16B row shift -> 2-way, free).
// ---------------------------------------------------------------------------
template<int NSPLIT, bool FINAL>
__global__ __launch_bounds__(256, 3) void attn_kernel(
    const unsigned short* __restrict__ proj,
    const unsigned short* __restrict__ qT,
    const float* __restrict__ x,
    const float* __restrict__ gamma_p,
    float* __restrict__ out,
    float* __restrict__ Opart,
    float* __restrict__ Lpart)
{
    constexpr int ITERS = 64 / NSPLIT;
    int bid = blockIdx.x;
    int h   = bid >> 8;          // n-split index
    int low = bid & 255;
    int xcd = low & 7;           // XCD-aware: batch pair per XCD for v L2 reuse
    int b = xcd >> 1;
    int mtile = ((low >> 3) << 1) | (xcd & 1);
    int m0 = mtile * 64;
    int nbase = h * (ITERS * 64);

    int tid = threadIdx.x;
    int w = tid >> 6, l = tid & 63, l15 = l & 15, lq = l >> 4;

    __shared__ alignas(16) unsigned short vs[256][72];  // [c][n]
    __shared__ alignas(16) unsigned short ps[64][72];   // [m][n]
    __shared__ float red[4][64];
    __shared__ float Ltot[64];

    const unsigned short* kbase = proj + ((size_t)b * PROJ_ROWS + C8) * NN;
    const unsigned short* vbase = proj + ((size_t)b * PROJ_ROWS + 64) * NN;
    const unsigned short* qbase = qT + (size_t)b * NN * C8;

    // k B-operand fragments for this m-tile (held all kernel)
    short8 kfrag[4];
#pragma unroll
    for (int mi = 0; mi < 4; mi++) {
        int col = m0 + mi * 16 + l15;
        unsigned short t8[8] __attribute__((aligned(16)));
#pragma unroll
        for (int j = 0; j < 8; j++)
            t8[j] = kbase[(size_t)(lq * 8 + j) * NN + col];
        kfrag[mi] = *(const short8*)t8;
    }

    f32x4 O[4][4];
#pragma unroll
    for (int ci = 0; ci < 4; ci++)
#pragma unroll
        for (int mi = 0; mi < 4; mi++) O[ci][mi] = (f32x4){0.f, 0.f, 0.f, 0.f};
    float runS[4] = {0.f, 0.f, 0.f, 0.f};

    // prologue: prefetch v tile 0, q frag 0; compute S for iter 0
    uint4 vreg[8];
#pragma unroll
    for (int i = 0; i < 8; i++) {
        int chunk = i * 256 + tid;
        int c = chunk >> 3, ch = chunk & 7;
        vreg[i] = *(const uint4*)(vbase + (size_t)c * NN + nbase + ch * 8);
    }
    short8 qfrag = *(const short8*)(qbase + (size_t)(nbase + 16 * w + l15) * C8 + lq * 8);
    f32x4 S[4];
#pragma unroll
    for (int mi = 0; mi < 4; mi++)
        S[mi] = __builtin_amdgcn_mfma_f32_16x16x32_bf16(
            qfrag, kfrag[mi], (f32x4){0.f, 0.f, 0.f, 0.f}, 0, 0, 0);

    for (int it = 0; it < ITERS; it++) {
        __syncthreads();  // previous PV done reading vs/ps
        // commit v tile
#pragma unroll
        for (int i = 0; i < 8; i++) {
            int chunk = i * 256 + tid;
            int c = chunk >> 3, ch = chunk & 7;
            *(uint4*)&vs[c][ch * 8] = vreg[i];
        }
        // P = exp(S) -> ps (B-operand layout), accumulate column-sum partials
#pragma unroll
        for (int mi = 0; mi < 4; mi++) {
            float p0 = __expf(S[mi][0]);
            float p1 = __expf(S[mi][1]);
            float p2 = __expf(S[mi][2]);
            float p3 = __expf(S[mi][3]);
            runS[mi] += (p0 + p1) + (p2 + p3);
            unsigned pk0 = (unsigned)f2bf(p0) | ((unsigned)f2bf(p1) << 16);
            unsigned pk1 = (unsigned)f2bf(p2) | ((unsigned)f2bf(p3) << 16);
            *(uint2*)&ps[mi * 16 + l15][16 * w + lq * 4] = make_uint2(pk0, pk1);
        }
        // prefetch next tiles (latency hidden by PV phase)
        if (it + 1 < ITERS) {
            int n0 = nbase + (it + 1) * 64;
#pragma unroll
            for (int i = 0; i < 8; i++) {
                int chunk = i * 256 + tid;
                int c = chunk >> 3, ch = chunk & 7;
                vreg[i] = *(const uint4*)(vbase + (size_t)c * NN + n0 + ch * 8);
            }
            qfrag = *(const short8*)(qbase + (size_t)(n0 + 16 * w + l15) * C8 + lq * 8);
        }
        __syncthreads();  // vs + ps visible

        // O[c,m] += V[c,n] . P[n,m] ; wave w owns c in [64w, 64w+64)
#pragma unroll
        for (int kh = 0; kh < 2; kh++) {
            short8 bfr[4];
#pragma unroll
            for (int mi = 0; mi < 4; mi++)
                bfr[mi] = *(const short8*)&ps[mi * 16 + l15][kh * 32 + lq * 8];
#pragma unroll
            for (int ci = 0; ci < 4; ci++) {
                short8 av = *(const short8*)&vs[64 * w + ci * 16 + l15][kh * 32 + lq * 8];
#pragma unroll
                for (int mi = 0; mi < 4; mi++)
                    O[ci][mi] = __builtin_amdgcn_mfma_f32_16x16x32_bf16(
                        av, bfr[mi], O[ci][mi], 0, 0, 0);
            }
        }
        // S for next iteration (independent of phase-A work)
        if (it + 1 < ITERS) {
#pragma unroll
            for (int mi = 0; mi < 4; mi++)
                S[mi] = __builtin_amdgcn_mfma_f32_16x16x32_bf16(
                    qfrag, kfrag[mi], (f32x4){0.f, 0.f, 0.f, 0.f}, 0, 0, 0);
        }
    }

    // column-sum reduction: cross-lane (n row-groups), then cross-wave
#pragma unroll
    for (int mi = 0; mi < 4; mi++) {
        float s = runS[mi];
        s += __shfl_xor(s, 16);
        s += __shfl_xor(s, 32);
        red[w][mi * 16 + l15] = s;
    }
    __syncthreads();
    if (tid < 64) Ltot[tid] = red[0][tid] + red[1][tid] + red[2][tid] + red[3][tid];
    __syncthreads();

    if constexpr (FINAL) {
        float gamma = gamma_p[0];
        float iv[4];
#pragma unroll
        for (int mi = 0; mi < 4; mi++) iv[mi] = 1.0f / Ltot[mi * 16 + l15];
#pragma unroll
        for (int ci = 0; ci < 4; ci++) {
#pragma unroll
            for (int mi = 0; mi < 4; mi++) {
                int m = m0 + mi * 16 + l15;
#pragma unroll
                for (int r = 0; r < 4; r++) {
                    int c = 64 * w + ci * 16 + lq * 4 + r;
                    size_t idx = ((size_t)b * CC + c) * NN + m;
                    out[idx] = gamma * (O[ci][mi][r] * iv[mi]) + x[idx];
                }
            }
        }
    } else {
        size_t p = ((size_t)h * BN + b) * 64 + mtile;
        if (tid < 64) Lpart[p * 64 + tid] = Ltot[tid];
        float* Ob = Opart + p * (size_t)(CC * 64);
#pragma unroll
        for (int ci = 0; ci < 4; ci++) {
#pragma unroll
            for (int mi = 0; mi < 4; mi++) {
#pragma unroll
                for (int r = 0; r < 4; r++) {
                    int c = 64 * w + ci * 16 + lq * 4 + r;
                    Ob[c * 64 + mi * 16 + l15] = O[ci][mi][r];
                }
            }
        }
    }
}

// ---------------------------------------------------------------------------
// Combine: out = gamma * (sum_h O_h) / (sum_h L_h) + x. One block per (b, mt).
// ---------------------------------------------------------------------------
template<int NSPLIT>
__global__ __launch_bounds__(256) void combine_kernel(
    const float* __restrict__ Opart, const float* __restrict__ Lpart,
    const float* __restrict__ x, const float* __restrict__ gamma_p,
    float* __restrict__ out)
{
    int bid = blockIdx.x;
    int b = bid >> 6, mt = bid & 63;
    int tid = threadIdx.x;
    int m4 = tid & 15, c16 = tid >> 4;
    float gamma = gamma_p[0];

    f32x4 Ls = (f32x4){0.f, 0.f, 0.f, 0.f};
#pragma unroll
    for (int h = 0; h < NSPLIT; h++) {
        size_t p = ((size_t)h * BN + b) * 64 + mt;
        Ls += *(const f32x4*)(Lpart + p * 64 + m4 * 4);
    }
    f32x4 inv;
#pragma unroll
    for (int j = 0; j < 4; j++) inv[j] = 1.0f / Ls[j];

    for (int cp = 0; cp < 16; cp++) {
        int c = cp * 16 + c16;
        f32x4 acc = (f32x4){0.f, 0.f, 0.f, 0.f};
#pragma unroll
        for (int h = 0; h < NSPLIT; h++) {
            size_t p = ((size_t)h * BN + b) * 64 + mt;
            acc += *(const f32x4*)(Opart + p * (size_t)(CC * 64) + c * 64 + m4 * 4);
        }
        size_t idx = ((size_t)b * CC + c) * NN + mt * 64 + m4 * 4;
        f32x4 xv = *(const f32x4*)(x + idx);
        f32x4 o;
#pragma unroll
        for (int j = 0; j < 4; j++) o[j] = gamma * (acc[j] * inv[j]) + xv[j];
        *(f32x4*)(out + idx) = o;
    }
}

extern "C" void kernel_launch(void* const* d_in, const int* in_sizes, int n_in,
                              void* d_out, int out_size, void* d_ws, size_t ws_size,
                              hipStream_t stream) {
    const float* x     = (const float*)d_in[0];
    const float* Wq    = (const float*)d_in[1];
    const float* bq    = (const float*)d_in[2];
    const float* Wk    = (const float*)d_in[3];
    const float* bk    = (const float*)d_in[4];
    const float* Wv    = (const float*)d_in[5];
    const float* bv    = (const float*)d_in[6];
    const float* gamma = (const float*)d_in[7];
    float* out = (float*)d_out;
    (void)in_sizes; (void)n_in; (void)out_size;

    unsigned short* proj = (unsigned short*)d_ws;
    unsigned short* qT   = proj + (size_t)BN * PROJ_ROWS * NN;
    const size_t baseB = ((size_t)BN * PROJ_ROWS * NN + (size_t)BN * NN * C8) * 2;  // 12.58 MB

    auto needB = [&](int ns) {
        size_t LpB = (size_t)ns * BN * 64 * 64 * 4;
        size_t OpB = (size_t)ns * BN * 64 * CC * 64 * 4;
        return baseB + LpB + OpB;
    };

    proj_kernel<<<320, 256, 0, stream>>>(x, Wq, bq, Wk, bk, Wv, bv, proj, qT);

    if (ws_size >= needB(4)) {
        float* Lpart = (float*)((char*)d_ws + baseB);
        float* Opart = Lpart + (size_t)4 * BN * 64 * 64;
        attn_kernel<4, false><<<1024, 256, 0, stream>>>(proj, qT, x, gamma, out, Opart, Lpart);
        combine_kernel<4><<<256, 256, 0, stream>>>(Opart, Lpart, x, gamma, out);
    } else if (ws_size >= needB(2)) {
        float* Lpart = (float*)((char*)d_ws + baseB);
        float* Opart = Lpart + (size_t)2 * BN * 64 * 64;
        attn_kernel<2, false><<<512, 256, 0, stream>>>(proj, qT, x, gamma, out, Opart, Lpart);
        combine_kernel<2><<<256, 256, 0, stream>>>(Opart, Lpart, x, gamma, out);
    } else {
        attn_kernel<1, true><<<256, 256, 0, stream>>>(proj, qT, x, gamma, out, nullptr, nullptr);
    }
}

// Round 3
// 196.425 us; speedup vs baseline: 1.8015x; 1.7029x over previous
//
#include <hip/hip_runtime.h>
#include <hip/hip_bf16.h>

#define BN 4
#define CC 256
#define C8 32
#define NN 4096
#define PROJ_ROWS 320

typedef __attribute__((ext_vector_type(8))) short short8;
typedef __attribute__((ext_vector_type(4))) float f32x4;

__device__ __forceinline__ unsigned short f2bf(float f) {
    unsigned u = __builtin_bit_cast(unsigned, f);
    unsigned r = (u + 0x7fffu + ((u >> 16) & 1u)) >> 16;
    return (unsigned short)r;
}

// ---------------------------------------------------------------------------
// Projection GEMM, x-read-once version.
// Block = (b, 64-wide n-tile); all 320 output rows computed per block.
// W A-fragments load straight from global (fp32 -> bf16 in-register);
// x staged once per 32-c chunk via float4, transposed into LDS.
// Grid: 4*64 = 256 blocks, 256 threads.
// ---------------------------------------------------------------------------
__global__ __launch_bounds__(256) void proj_kernel(
    const float* __restrict__ x,
    const float* __restrict__ Wq, const float* __restrict__ bq,
    const float* __restrict__ Wk, const float* __restrict__ bk,
    const float* __restrict__ Wv, const float* __restrict__ bv,
    unsigned short* __restrict__ proj, unsigned short* __restrict__ qT)
{
    int bid = blockIdx.x;
    int b = bid >> 6, nt = bid & 63;
    int n0 = nt * 64;
    int tid = threadIdx.x;
    int w = tid >> 6, l = tid & 63, l15 = l & 15, lq = l >> 4;

    // Xt[n 64][c 32], stride 40 shorts = 80 B (16B-aligned rows, 2-way banks)
    __shared__ alignas(16) unsigned short Xt[64][40];

    f32x4 acc[5][4];   // wave owns o-groups g = 5w..5w+4 (16 rows each)
#pragma unroll
    for (int gi = 0; gi < 5; gi++)
#pragma unroll
        for (int mi = 0; mi < 4; mi++) acc[gi][mi] = (f32x4){0.f, 0.f, 0.f, 0.f};

    int c_l = tid >> 3;          // 0..31
    int nb  = (tid & 7) * 8;     // 0..56

    for (int kc = 0; kc < 8; kc++) {
        __syncthreads();  // WAR on Xt
        // stage x chunk [32 c][64 n] -> Xt[n][c]
        {
            const float* xp = x + ((size_t)(b * CC + kc * 32 + c_l)) * NN + n0 + nb;
            float4 x0 = *(const float4*)xp;
            float4 x1 = *(const float4*)(xp + 4);
            float t[8] = {x0.x, x0.y, x0.z, x0.w, x1.x, x1.y, x1.z, x1.w};
#pragma unroll
            for (int e = 0; e < 8; e++) Xt[nb + e][c_l] = f2bf(t[e]);
        }
        __syncthreads();

        // load all W fragments for this kc first (pipeline the global loads)
        float4 wf[5][2];
#pragma unroll
        for (int gi = 0; gi < 5; gi++) {
            int og = (w * 5 + gi) * 16 + l15;
            const float* wrow = (og < 32) ? (Wq + (size_t)og * CC)
                              : (og < 64) ? (Wk + (size_t)(og - 32) * CC)
                                          : (Wv + (size_t)(og - 64) * CC);
            const float* wp = wrow + kc * 32 + lq * 8;
            wf[gi][0] = *(const float4*)wp;
            wf[gi][1] = *(const float4*)(wp + 4);
        }
#pragma unroll
        for (int gi = 0; gi < 5; gi++) {
            unsigned short a8[8] __attribute__((aligned(16)));
            float tw[8] = {wf[gi][0].x, wf[gi][0].y, wf[gi][0].z, wf[gi][0].w,
                           wf[gi][1].x, wf[gi][1].y, wf[gi][1].z, wf[gi][1].w};
#pragma unroll
            for (int e = 0; e < 8; e++) a8[e] = f2bf(tw[e]);
            short8 af = *(const short8*)a8;
#pragma unroll
            for (int mi = 0; mi < 4; mi++) {
                short8 bf = *(const short8*)&Xt[mi * 16 + l15][lq * 8];
                acc[gi][mi] = __builtin_amdgcn_mfma_f32_16x16x32_bf16(af, bf, acc[gi][mi], 0, 0, 0);
            }
        }
    }

    // epilogue: bias + bf16 store. C/D: row = lq*4+r (within group), col = l15.
#pragma unroll
    for (int gi = 0; gi < 5; gi++) {
#pragma unroll
        for (int r = 0; r < 4; r++) {
            int og = (w * 5 + gi) * 16 + lq * 4 + r;
            float bias = (og < 32) ? bq[og] : (og < 64) ? bk[og - 32] : bv[og - 64];
#pragma unroll
            for (int mi = 0; mi < 4; mi++) {
                int n = n0 + mi * 16 + l15;
                unsigned short v16 = f2bf(acc[gi][mi][r] + bias);
                if (og < 32) {
                    qT[((size_t)b * NN + n) * C8 + og] = v16;
                } else {
                    proj[((size_t)b * PROJ_ROWS + og) * NN + n] = v16;
                }
            }
        }
    }
}

// ---------------------------------------------------------------------------
// Flash attention over the query axis (softmax over n), no max subtraction
// (|S| < ~40, exp safe in fp32; shift-invariance => identical result).
// LDS holds ONLY the 9 KB P exchange. v A-fragments and q A-fragments load
// straight from global; no global load is in flight across any barrier.
// ---------------------------------------------------------------------------
template<int NSPLIT, bool FINAL>
__global__ __launch_bounds__(256, 3) void attn_kernel(
    const unsigned short* __restrict__ proj,
    const unsigned short* __restrict__ qT,
    const float* __restrict__ x,
    const float* __restrict__ gamma_p,
    float* __restrict__ out,
    float* __restrict__ Opart,
    float* __restrict__ Lpart)
{
    constexpr int ITERS = 64 / NSPLIT;
    int bid = blockIdx.x;
    int h   = bid >> 8;
    int low = bid & 255;
    int xcd = low & 7;
    int b = xcd >> 1;
    int mtile = ((low >> 3) << 1) | (xcd & 1);
    int m0 = mtile * 64;
    int nbase = h * (ITERS * 64);

    int tid = threadIdx.x;
    int w = tid >> 6, l = tid & 63, l15 = l & 15, lq = l >> 4;

    __shared__ alignas(16) unsigned short ps[64][72];  // [m][n], 144 B rows
    __shared__ float red[4][64];
    __shared__ float Ltot[64];

    const unsigned short* kbase = proj + ((size_t)b * PROJ_ROWS + C8) * NN;
    const unsigned short* vbase = proj + ((size_t)b * PROJ_ROWS + 64) * NN;
    const unsigned short* qbase = qT + (size_t)b * NN * C8;

    // k B-operand fragments (held all kernel): lane = k[c8=lq*8+j][m]
    short8 kfrag[4];
#pragma unroll
    for (int mi = 0; mi < 4; mi++) {
        int col = m0 + mi * 16 + l15;
        unsigned short t8[8] __attribute__((aligned(16)));
#pragma unroll
        for (int j = 0; j < 8; j++)
            t8[j] = kbase[(size_t)(lq * 8 + j) * NN + col];
        kfrag[mi] = *(const short8*)t8;
    }

    f32x4 O[4][4];
#pragma unroll
    for (int ci = 0; ci < 4; ci++)
#pragma unroll
        for (int mi = 0; mi < 4; mi++) O[ci][mi] = (f32x4){0.f, 0.f, 0.f, 0.f};
    float runS[4] = {0.f, 0.f, 0.f, 0.f};

    // S for iteration 0 (wave w owns n-rows [16w,16w+16) of the tile)
    short8 qfrag = *(const short8*)(qbase + (size_t)(nbase + 16 * w + l15) * C8 + lq * 8);
    f32x4 S[4];
#pragma unroll
    for (int mi = 0; mi < 4; mi++)
        S[mi] = __builtin_amdgcn_mfma_f32_16x16x32_bf16(
            qfrag, kfrag[mi], (f32x4){0.f, 0.f, 0.f, 0.f}, 0, 0, 0);

    for (int it = 0; it < ITERS; it++) {
        int n0c = nbase + it * 64;
        __syncthreads();  // WAR: previous PV done reading ps
        // P = exp(S) -> ps (B-operand layout), accumulate column-sum partials
#pragma unroll
        for (int mi = 0; mi < 4; mi++) {
            float p0 = __expf(S[mi][0]);
            float p1 = __expf(S[mi][1]);
            float p2 = __expf(S[mi][2]);
            float p3 = __expf(S[mi][3]);
            runS[mi] += (p0 + p1) + (p2 + p3);
            unsigned pk0 = (unsigned)f2bf(p0) | ((unsigned)f2bf(p1) << 16);
            unsigned pk1 = (unsigned)f2bf(p2) | ((unsigned)f2bf(p3) << 16);
            *(uint2*)&ps[mi * 16 + l15][16 * w + lq * 4] = make_uint2(pk0, pk1);
        }
        __syncthreads();  // ps visible

        // q prefetch for next S — issued here, consumed AFTER the PV phase,
        // before the next barrier (never drained by a barrier).
        short8 qnext;
        if (it + 1 < ITERS)
            qnext = *(const short8*)(qbase + (size_t)(n0c + 64 + 16 * w + l15) * C8 + lq * 8);

        // PV: O[c,m] += V[c,n] . P[n,m]; wave w owns c in [64w,64w+64).
        // av loads issued and consumed entirely inside this phase.
#pragma unroll
        for (int kh = 0; kh < 2; kh++) {
            short8 av[4];
#pragma unroll
            for (int ci = 0; ci < 4; ci++)
                av[ci] = *(const short8*)(vbase
                         + (size_t)(64 * w + ci * 16 + l15) * NN + n0c + kh * 32 + lq * 8);
            short8 bfr[4];
#pragma unroll
            for (int mi = 0; mi < 4; mi++)
                bfr[mi] = *(const short8*)&ps[mi * 16 + l15][kh * 32 + lq * 8];
#pragma unroll
            for (int ci = 0; ci < 4; ci++)
#pragma unroll
                for (int mi = 0; mi < 4; mi++)
                    O[ci][mi] = __builtin_amdgcn_mfma_f32_16x16x32_bf16(
                        av[ci], bfr[mi], O[ci][mi], 0, 0, 0);
        }

        // S for next iteration
        if (it + 1 < ITERS) {
            qfrag = qnext;
#pragma unroll
            for (int mi = 0; mi < 4; mi++)
                S[mi] = __builtin_amdgcn_mfma_f32_16x16x32_bf16(
                    qfrag, kfrag[mi], (f32x4){0.f, 0.f, 0.f, 0.f}, 0, 0, 0);
        }
    }

    // column-sum reduction: cross-lane (n row-groups), then cross-wave
#pragma unroll
    for (int mi = 0; mi < 4; mi++) {
        float s = runS[mi];
        s += __shfl_xor(s, 16);
        s += __shfl_xor(s, 32);
        red[w][mi * 16 + l15] = s;
    }
    __syncthreads();
    if (tid < 64) Ltot[tid] = red[0][tid] + red[1][tid] + red[2][tid] + red[3][tid];
    __syncthreads();

    if constexpr (FINAL) {
        float gamma = gamma_p[0];
        float iv[4];
#pragma unroll
        for (int mi = 0; mi < 4; mi++) iv[mi] = 1.0f / Ltot[mi * 16 + l15];
#pragma unroll
        for (int ci = 0; ci < 4; ci++) {
#pragma unroll
            for (int mi = 0; mi < 4; mi++) {
                int m = m0 + mi * 16 + l15;
#pragma unroll
                for (int r = 0; r < 4; r++) {
                    int c = 64 * w + ci * 16 + lq * 4 + r;
                    size_t idx = ((size_t)b * CC + c) * NN + m;
                    out[idx] = gamma * (O[ci][mi][r] * iv[mi]) + x[idx];
                }
            }
        }
    } else {
        size_t p = ((size_t)h * BN + b) * 64 + mtile;
        if (tid < 64) Lpart[p * 64 + tid] = Ltot[tid];
        float* Ob = Opart + p * (size_t)(CC * 64);
#pragma unroll
        for (int ci = 0; ci < 4; ci++) {
#pragma unroll
            for (int mi = 0; mi < 4; mi++) {
#pragma unroll
                for (int r = 0; r < 4; r++) {
                    int c = 64 * w + ci * 16 + lq * 4 + r;
                    Ob[c * 64 + mi * 16 + l15] = O[ci][mi][r];
                }
            }
        }
    }
}

// ---------------------------------------------------------------------------
// Combine: out = gamma * (sum_h O_h) / (sum_h L_h) + x. One block per (b, mt).
// ---------------------------------------------------------------------------
template<int NSPLIT>
__global__ __launch_bounds__(256) void combine_kernel(
    const float* __restrict__ Opart, const float* __restrict__ Lpart,
    const float* __restrict__ x, const float* __restrict__ gamma_p,
    float* __restrict__ out)
{
    int bid = blockIdx.x;
    int b = bid >> 6, mt = bid & 63;
    int tid = threadIdx.x;
    int m4 = tid & 15, c16 = tid >> 4;
    float gamma = gamma_p[0];

    f32x4 Ls = (f32x4){0.f, 0.f, 0.f, 0.f};
#pragma unroll
    for (int h = 0; h < NSPLIT; h++) {
        size_t p = ((size_t)h * BN + b) * 64 + mt;
        Ls += *(const f32x4*)(Lpart + p * 64 + m4 * 4);
    }
    f32x4 inv;
#pragma unroll
    for (int j = 0; j < 4; j++) inv[j] = 1.0f / Ls[j];

    for (int cp = 0; cp < 16; cp++) {
        int c = cp * 16 + c16;
        f32x4 acc = (f32x4){0.f, 0.f, 0.f, 0.f};
#pragma unroll
        for (int h = 0; h < NSPLIT; h++) {
            size_t p = ((size_t)h * BN + b) * 64 + mt;
            acc += *(const f32x4*)(Opart + p * (size_t)(CC * 64) + c * 64 + m4 * 4);
        }
        size_t idx = ((size_t)b * CC + c) * NN + mt * 64 + m4 * 4;
        f32x4 xv = *(const f32x4*)(x + idx);
        f32x4 o;
#pragma unroll
        for (int j = 0; j < 4; j++) o[j] = gamma * (acc[j] * inv[j]) + xv[j];
        *(f32x4*)(out + idx) = o;
    }
}

extern "C" void kernel_launch(void* const* d_in, const int* in_sizes, int n_in,
                              void* d_out, int out_size, void* d_ws, size_t ws_size,
                              hipStream_t stream) {
    const float* x     = (const float*)d_in[0];
    const float* Wq    = (const float*)d_in[1];
    const float* bq    = (const float*)d_in[2];
    const float* Wk    = (const float*)d_in[3];
    const float* bk    = (const float*)d_in[4];
    const float* Wv    = (const float*)d_in[5];
    const float* bv    = (const float*)d_in[6];
    const float* gamma = (const float*)d_in[7];
    float* out = (float*)d_out;
    (void)in_sizes; (void)n_in; (void)out_size;

    unsigned short* proj = (unsigned short*)d_ws;
    unsigned short* qT   = proj + (size_t)BN * PROJ_ROWS * NN;
    const size_t baseB = ((size_t)BN * PROJ_ROWS * NN + (size_t)BN * NN * C8) * 2;

    auto needB = [&](int ns) {
        size_t LpB = (size_t)ns * BN * 64 * 64 * 4;
        size_t OpB = (size_t)ns * BN * 64 * CC * 64 * 4;
        return baseB + LpB + OpB;
    };

    proj_kernel<<<256, 256, 0, stream>>>(x, Wq, bq, Wk, bk, Wv, bv, proj, qT);

    if (ws_size >= needB(4)) {
        float* Lpart = (float*)((char*)d_ws + baseB);
        float* Opart = Lpart + (size_t)4 * BN * 64 * 64;
        attn_kernel<4, false><<<1024, 256, 0, stream>>>(proj, qT, x, gamma, out, Opart, Lpart);
        combine_kernel<4><<<256, 256, 0, stream>>>(Opart, Lpart, x, gamma, out);
    } else if (ws_size >= needB(2)) {
        float* Lpart = (float*)((char*)d_ws + baseB);
        float* Opart = Lpart + (size_t)2 * BN * 64 * 64;
        attn_kernel<2, false><<<512, 256, 0, stream>>>(proj, qT, x, gamma, out, Opart, Lpart);
        combine_kernel<2><<<256, 256, 0, stream>>>(Opart, Lpart, x, gamma, out);
    } else {
        attn_kernel<1, true><<<256, 256, 0, stream>>>(proj, qT, x, gamma, out, nullptr, nullptr);
    }
}

// Round 4
// 181.667 us; speedup vs baseline: 1.9479x; 1.0812x over previous
//
#include <hip/hip_runtime.h>
#include <hip/hip_bf16.h>

#define BN 4
#define CC 256
#define C8 32
#define NN 4096
#define PROJ_ROWS 320

typedef __attribute__((ext_vector_type(8))) short short8;
typedef __attribute__((ext_vector_type(4))) float f32x4;

__device__ __forceinline__ unsigned short f2bf(float f) {
    unsigned u = __builtin_bit_cast(unsigned, f);
    unsigned r = (u + 0x7fffu + ((u >> 16) & 1u)) >> 16;
    return (unsigned short)r;
}

// ---------------------------------------------------------------------------
// Projection GEMM, single-barrier version.
// Block = (b, 64-wide n-tile). Stage ALL 256 c of the x tile into LDS once
// (34 KB), one barrier, then a straight-line 160-MFMA body (W A-fragments
// loaded from global, L2-hot, fp32->bf16 in-register). Grid: 256 blocks.
// ---------------------------------------------------------------------------
__global__ __launch_bounds__(256) void proj_kernel(
    const float* __restrict__ x,
    const float* __restrict__ Wq, const float* __restrict__ bq,
    const float* __restrict__ Wk, const float* __restrict__ bk,
    const float* __restrict__ Wv, const float* __restrict__ bv,
    unsigned short* __restrict__ proj, unsigned short* __restrict__ qT)
{
    int bid = blockIdx.x;
    int b = bid >> 6, nt = bid & 63;
    int n0 = nt * 64;
    int tid = threadIdx.x;
    int w = tid >> 6, l = tid & 63, l15 = l & 15, lq = l >> 4;

    // Xt[n 64][c 256], stride 264 shorts = 528 B (16B-aligned rows)
    __shared__ alignas(16) unsigned short Xt[64][264];

    int c_l = tid >> 3;          // 0..31
    int nb  = (tid & 7) * 8;     // 0..56

    // stage all 8 c-chunks, then ONE barrier
#pragma unroll
    for (int kc = 0; kc < 8; kc++) {
        const float* xp = x + ((size_t)(b * CC + kc * 32 + c_l)) * NN + n0 + nb;
        float4 x0 = *(const float4*)xp;
        float4 x1 = *(const float4*)(xp + 4);
        float t[8] = {x0.x, x0.y, x0.z, x0.w, x1.x, x1.y, x1.z, x1.w};
#pragma unroll
        for (int e = 0; e < 8; e++) Xt[nb + e][kc * 32 + c_l] = f2bf(t[e]);
    }
    __syncthreads();

    f32x4 acc[5][4];   // wave owns o-groups g = 5w..5w+4 (16 rows each)
#pragma unroll
    for (int gi = 0; gi < 5; gi++)
#pragma unroll
        for (int mi = 0; mi < 4; mi++) acc[gi][mi] = (f32x4){0.f, 0.f, 0.f, 0.f};

    for (int kc = 0; kc < 8; kc++) {
        float4 wf[5][2];
#pragma unroll
        for (int gi = 0; gi < 5; gi++) {
            int og = (w * 5 + gi) * 16 + l15;
            const float* wrow = (og < 32) ? (Wq + (size_t)og * CC)
                              : (og < 64) ? (Wk + (size_t)(og - 32) * CC)
                                          : (Wv + (size_t)(og - 64) * CC);
            const float* wp = wrow + kc * 32 + lq * 8;
            wf[gi][0] = *(const float4*)wp;
            wf[gi][1] = *(const float4*)(wp + 4);
        }
#pragma unroll
        for (int gi = 0; gi < 5; gi++) {
            unsigned short a8[8] __attribute__((aligned(16)));
            float tw[8] = {wf[gi][0].x, wf[gi][0].y, wf[gi][0].z, wf[gi][0].w,
                           wf[gi][1].x, wf[gi][1].y, wf[gi][1].z, wf[gi][1].w};
#pragma unroll
            for (int e = 0; e < 8; e++) a8[e] = f2bf(tw[e]);
            short8 af = *(const short8*)a8;
#pragma unroll
            for (int mi = 0; mi < 4; mi++) {
                short8 bf = *(const short8*)&Xt[mi * 16 + l15][kc * 32 + lq * 8];
                acc[gi][mi] = __builtin_amdgcn_mfma_f32_16x16x32_bf16(af, bf, acc[gi][mi], 0, 0, 0);
            }
        }
    }

    // epilogue: bias + bf16 store. C/D: row = lq*4+r (within group), col = l15.
#pragma unroll
    for (int gi = 0; gi < 5; gi++) {
#pragma unroll
        for (int r = 0; r < 4; r++) {
            int og = (w * 5 + gi) * 16 + lq * 4 + r;
            float bias = (og < 32) ? bq[og] : (og < 64) ? bk[og - 32] : bv[og - 64];
#pragma unroll
            for (int mi = 0; mi < 4; mi++) {
                int n = n0 + mi * 16 + l15;
                unsigned short v16 = f2bf(acc[gi][mi][r] + bias);
                if (og < 32) {
                    qT[((size_t)b * NN + n) * C8 + og] = v16;
                } else {
                    proj[((size_t)b * PROJ_ROWS + og) * NN + n] = v16;
                }
            }
        }
    }
}

// ---------------------------------------------------------------------------
// Flash attention over the query axis (softmax over n), no max subtraction.
// ONE barrier per 64-n iteration: ps is double-buffered; loop body is
//   barrier -> PV(ps[it&1]) -> S_{it+1} -> exp -> write ps[(it+1)&1].
// WAR on ps[buf] is covered by the barrier (a wave reaches the iter-i+2
// write only after the iter-i+1 barrier, which requires all waves to have
// finished iter-i PV reads). No global load is in flight across a barrier.
// ---------------------------------------------------------------------------
template<int NSPLIT, bool FINAL>
__global__ __launch_bounds__(256, 4) void attn_kernel(
    const unsigned short* __restrict__ proj,
    const unsigned short* __restrict__ qT,
    const float* __restrict__ x,
    const float* __restrict__ gamma_p,
    float* __restrict__ out,
    float* __restrict__ Opart,
    float* __restrict__ Lpart)
{
    constexpr int ITERS = 64 / NSPLIT;
    int bid = blockIdx.x;
    int h   = bid >> 8;
    int low = bid & 255;
    int xcd = low & 7;
    int b = xcd >> 1;
    int mtile = ((low >> 3) << 1) | (xcd & 1);
    int m0 = mtile * 64;
    int nbase = h * (ITERS * 64);

    int tid = threadIdx.x;
    int w = tid >> 6, l = tid & 63, l15 = l & 15, lq = l >> 4;

    __shared__ alignas(16) unsigned short ps[2][64][72];  // [buf][m][n]
    __shared__ float red[4][64];
    __shared__ float Ltot[64];

    const unsigned short* kbase = proj + ((size_t)b * PROJ_ROWS + C8) * NN;
    const unsigned short* vbase = proj + ((size_t)b * PROJ_ROWS + 64) * NN;
    const unsigned short* qbase = qT + (size_t)b * NN * C8;

    // k B-operand fragments (held all kernel): lane = k[c8=lq*8+j][m]
    short8 kfrag[4];
#pragma unroll
    for (int mi = 0; mi < 4; mi++) {
        int col = m0 + mi * 16 + l15;
        unsigned short t8[8] __attribute__((aligned(16)));
#pragma unroll
        for (int j = 0; j < 8; j++)
            t8[j] = kbase[(size_t)(lq * 8 + j) * NN + col];
        kfrag[mi] = *(const short8*)t8;
    }

    f32x4 O[4][4];
#pragma unroll
    for (int ci = 0; ci < 4; ci++)
#pragma unroll
        for (int mi = 0; mi < 4; mi++) O[ci][mi] = (f32x4){0.f, 0.f, 0.f, 0.f};
    float runS[4] = {0.f, 0.f, 0.f, 0.f};

    // prologue: S_0, exp, write ps[0]
    {
        short8 qfrag = *(const short8*)(qbase + (size_t)(nbase + 16 * w + l15) * C8 + lq * 8);
#pragma unroll
        for (int mi = 0; mi < 4; mi++) {
            f32x4 S = __builtin_amdgcn_mfma_f32_16x16x32_bf16(
                qfrag, kfrag[mi], (f32x4){0.f, 0.f, 0.f, 0.f}, 0, 0, 0);
            float p0 = __expf(S[0]);
            float p1 = __expf(S[1]);
            float p2 = __expf(S[2]);
            float p3 = __expf(S[3]);
            runS[mi] += (p0 + p1) + (p2 + p3);
            unsigned pk0 = (unsigned)f2bf(p0) | ((unsigned)f2bf(p1) << 16);
            unsigned pk1 = (unsigned)f2bf(p2) | ((unsigned)f2bf(p3) << 16);
            *(uint2*)&ps[0][mi * 16 + l15][16 * w + lq * 4] = make_uint2(pk0, pk1);
        }
    }

    for (int it = 0; it < ITERS; it++) {
        int n0c = nbase + it * 64;
        __syncthreads();  // ps[it&1] visible; WAR on ps[(it+1)&1] cleared

        // PV: O[c,m] += V[c,n] . P[n,m]; wave w owns c in [64w,64w+64).
        const unsigned short* psrc = &ps[it & 1][0][0];
#pragma unroll
        for (int kh = 0; kh < 2; kh++) {
            short8 av[4];
#pragma unroll
            for (int ci = 0; ci < 4; ci++)
                av[ci] = *(const short8*)(vbase
                         + (size_t)(64 * w + ci * 16 + l15) * NN + n0c + kh * 32 + lq * 8);
            short8 bfr[4];
#pragma unroll
            for (int mi = 0; mi < 4; mi++)
                bfr[mi] = *(const short8*)(psrc + (mi * 16 + l15) * 72 + kh * 32 + lq * 8);
#pragma unroll
            for (int ci = 0; ci < 4; ci++)
#pragma unroll
                for (int mi = 0; mi < 4; mi++)
                    O[ci][mi] = __builtin_amdgcn_mfma_f32_16x16x32_bf16(
                        av[ci], bfr[mi], O[ci][mi], 0, 0, 0);
        }

        // S_{it+1}, exp, write ps[(it+1)&1] — hidden until next barrier
        if (it + 1 < ITERS) {
            short8 qfrag = *(const short8*)(qbase
                           + (size_t)(n0c + 64 + 16 * w + l15) * C8 + lq * 8);
            unsigned short* pdst = &ps[(it + 1) & 1][0][0];
#pragma unroll
            for (int mi = 0; mi < 4; mi++) {
                f32x4 S = __builtin_amdgcn_mfma_f32_16x16x32_bf16(
                    qfrag, kfrag[mi], (f32x4){0.f, 0.f, 0.f, 0.f}, 0, 0, 0);
                float p0 = __expf(S[0]);
                float p1 = __expf(S[1]);
                float p2 = __expf(S[2]);
                float p3 = __expf(S[3]);
                runS[mi] += (p0 + p1) + (p2 + p3);
                unsigned pk0 = (unsigned)f2bf(p0) | ((unsigned)f2bf(p1) << 16);
                unsigned pk1 = (unsigned)f2bf(p2) | ((unsigned)f2bf(p3) << 16);
                *(uint2*)(pdst + (mi * 16 + l15) * 72 + 16 * w + lq * 4) = make_uint2(pk0, pk1);
            }
        }
    }

    // column-sum reduction: cross-lane (n row-groups), then cross-wave
#pragma unroll
    for (int mi = 0; mi < 4; mi++) {
        float s = runS[mi];
        s += __shfl_xor(s, 16);
        s += __shfl_xor(s, 32);
        red[w][mi * 16 + l15] = s;
    }
    __syncthreads();
    if (tid < 64) Ltot[tid] = red[0][tid] + red[1][tid] + red[2][tid] + red[3][tid];
    __syncthreads();

    if constexpr (FINAL) {
        float gamma = gamma_p[0];
        float iv[4];
#pragma unroll
        for (int mi = 0; mi < 4; mi++) iv[mi] = 1.0f / Ltot[mi * 16 + l15];
#pragma unroll
        for (int ci = 0; ci < 4; ci++) {
#pragma unroll
            for (int mi = 0; mi < 4; mi++) {
                int m = m0 + mi * 16 + l15;
#pragma unroll
                for (int r = 0; r < 4; r++) {
                    int c = 64 * w + ci * 16 + lq * 4 + r;
                    size_t idx = ((size_t)b * CC + c) * NN + m;
                    out[idx] = gamma * (O[ci][mi][r] * iv[mi]) + x[idx];
                }
            }
        }
    } else {
        size_t p = ((size_t)h * BN + b) * 64 + mtile;
        if (tid < 64) Lpart[p * 64 + tid] = Ltot[tid];
        float* Ob = Opart + p * (size_t)(CC * 64);
#pragma unroll
        for (int ci = 0; ci < 4; ci++) {
#pragma unroll
            for (int mi = 0; mi < 4; mi++) {
#pragma unroll
                for (int r = 0; r < 4; r++) {
                    int c = 64 * w + ci * 16 + lq * 4 + r;
                    Ob[c * 64 + mi * 16 + l15] = O[ci][mi][r];
                }
            }
        }
    }
}

// ---------------------------------------------------------------------------
// Combine: out = gamma * (sum_h O_h) / (sum_h L_h) + x.
// Grid 1024: one block per (b, mt, c-quarter) for >1 block/CU.
// ---------------------------------------------------------------------------
template<int NSPLIT>
__global__ __launch_bounds__(256) void combine_kernel(
    const float* __restrict__ Opart, const float* __restrict__ Lpart,
    const float* __restrict__ x, const float* __restrict__ gamma_p,
    float* __restrict__ out)
{
    int bid = blockIdx.x;
    int cq = bid & 3;
    int mt = (bid >> 2) & 63;
    int b  = bid >> 8;
    int tid = threadIdx.x;
    int m4 = tid & 15, c16 = tid >> 4;
    float gamma = gamma_p[0];

    f32x4 Ls = (f32x4){0.f, 0.f, 0.f, 0.f};
#pragma unroll
    for (int h = 0; h < NSPLIT; h++) {
        size_t p = ((size_t)h * BN + b) * 64 + mt;
        Ls += *(const f32x4*)(Lpart + p * 64 + m4 * 4);
    }
    f32x4 inv;
#pragma unroll
    for (int j = 0; j < 4; j++) inv[j] = 1.0f / Ls[j];

#pragma unroll
    for (int cp = 0; cp < 4; cp++) {
        int c = cq * 64 + cp * 16 + c16;
        f32x4 acc = (f32x4){0.f, 0.f, 0.f, 0.f};
#pragma unroll
        for (int h = 0; h < NSPLIT; h++) {
            size_t p = ((size_t)h * BN + b) * 64 + mt;
            acc += *(const f32x4*)(Opart + p * (size_t)(CC * 64) + c * 64 + m4 * 4);
        }
        size_t idx = ((size_t)b * CC + c) * NN + mt * 64 + m4 * 4;
        f32x4 xv = *(const f32x4*)(x + idx);
        f32x4 o;
#pragma unroll
        for (int j = 0; j < 4; j++) o[j] = gamma * (acc[j] * inv[j]) + xv[j];
        *(f32x4*)(out + idx) = o;
    }
}

extern "C" void kernel_launch(void* const* d_in, const int* in_sizes, int n_in,
                              void* d_out, int out_size, void* d_ws, size_t ws_size,
                              hipStream_t stream) {
    const float* x     = (const float*)d_in[0];
    const float* Wq    = (const float*)d_in[1];
    const float* bq    = (const float*)d_in[2];
    const float* Wk    = (const float*)d_in[3];
    const float* bk    = (const float*)d_in[4];
    const float* Wv    = (const float*)d_in[5];
    const float* bv    = (const float*)d_in[6];
    const float* gamma = (const float*)d_in[7];
    float* out = (float*)d_out;
    (void)in_sizes; (void)n_in; (void)out_size;

    unsigned short* proj = (unsigned short*)d_ws;
    unsigned short* qT   = proj + (size_t)BN * PROJ_ROWS * NN;
    const size_t baseB = ((size_t)BN * PROJ_ROWS * NN + (size_t)BN * NN * C8) * 2;

    auto needB = [&](int ns) {
        size_t LpB = (size_t)ns * BN * 64 * 64 * 4;
        size_t OpB = (size_t)ns * BN * 64 * CC * 64 * 4;
        return baseB + LpB + OpB;
    };

    proj_kernel<<<256, 256, 0, stream>>>(x, Wq, bq, Wk, bk, Wv, bv, proj, qT);

    if (ws_size >= needB(4)) {
        float* Lpart = (float*)((char*)d_ws + baseB);
        float* Opart = Lpart + (size_t)4 * BN * 64 * 64;
        attn_kernel<4, false><<<1024, 256, 0, stream>>>(proj, qT, x, gamma, out, Opart, Lpart);
        combine_kernel<4><<<1024, 256, 0, stream>>>(Opart, Lpart, x, gamma, out);
    } else if (ws_size >= needB(2)) {
        float* Lpart = (float*)((char*)d_ws + baseB);
        float* Opart = Lpart + (size_t)2 * BN * 64 * 64;
        attn_kernel<2, false><<<512, 256, 0, stream>>>(proj, qT, x, gamma, out, Opart, Lpart);
        combine_kernel<2><<<1024, 256, 0, stream>>>(Opart, Lpart, x, gamma, out);
    } else {
        attn_kernel<1, true><<<256, 256, 0, stream>>>(proj, qT, x, gamma, out, nullptr, nullptr);
    }
}